// Round 8
// baseline (676.347 us; speedup 1.0000x reference)
//
#include <hip/hip_runtime.h>
#include <math.h>

namespace {

constexpr int B_ = 4;
constexpr int C_ = 256;
constexpr int C4_ = 64;
constexpr int N_ = 4096;

typedef __attribute__((ext_vector_type(8))) short bf16x8;
typedef __attribute__((ext_vector_type(4))) float f32x4;

__device__ __forceinline__ unsigned short bf16_rne(float f) {
    unsigned u = __float_as_uint(f);
    u += 0x7fffu + ((u >> 16) & 1u);
    return (unsigned short)(u >> 16);
}
__device__ __forceinline__ float bf16_to_f(unsigned short s) {
    return __uint_as_float(((unsigned)s) << 16);
}

__global__ __launch_bounds__(256) void zero_kernel(float* __restrict__ p) {
    p[blockIdx.x * 256 + threadIdx.x] = 0.0f;
}

// wq||wv -> wcomb bf16 [320,256]; wt -> wtb bf16 [256,256].
__global__ __launch_bounds__(256) void cvt_kernel(
        const float* __restrict__ wq, const float* __restrict__ wv,
        const float* __restrict__ wt, unsigned short* __restrict__ wcomb,
        unsigned short* __restrict__ wtb) {
    const int i = (blockIdx.x * 256 + threadIdx.x) * 4;
    const float* src;
    unsigned short* dst;
    if (i < 16384) { src = wq + i; dst = wcomb + i; }
    else if (i < 81920) { src = wv + (i - 16384); dst = wcomb + i; }
    else { src = wt + (i - 81920); dst = wtb + (i - 81920); }
    const float4 f = *reinterpret_cast<const float4*>(src);
    ushort4 u;
    u.x = bf16_rne(f.x); u.y = bf16_rne(f.y);
    u.z = bf16_rne(f.z); u.w = bf16_rne(f.w);
    *reinterpret_cast<ushort4*>(dst) = u;
}

// Small-block MFMA projection: grid (64 ntiles, 4 o-quarters, B). 256 thr.
__global__ __launch_bounds__(256) void proj_kernel(
        const float* __restrict__ x, const unsigned short* __restrict__ wcomb,
        const float* __restrict__ bv, unsigned short* __restrict__ qkT,
        unsigned short* __restrict__ v) {
    __shared__ unsigned short xs[2][64][36];
    const int n0 = blockIdx.x * 64;
    const int oq = blockIdx.y;
    const int b = blockIdx.z;
    const int tid = threadIdx.x;
    const int wave = tid >> 6, lane = tid & 63;
    const int quad = lane >> 4, l15 = lane & 15;
    f32x4 acc[5];
#pragma unroll
    for (int ot = 0; ot < 5; ++ot) acc[ot] = (f32x4){0.f, 0.f, 0.f, 0.f};
    // stage chunk 0
#pragma unroll
    for (int k = 0; k < 8; ++k) {
        const int i = tid + k * 256;
        const int c = i >> 6, n2 = i & 63;
        xs[0][n2][c] = bf16_rne(x[((size_t)b * C_ + c) * N_ + n0 + n2]);
    }
    __syncthreads();
    for (int ch = 0; ch < 8; ++ch) {
        const int buf = ch & 1;
        float pre[8];
        if (ch < 7) {
#pragma unroll
            for (int k = 0; k < 8; ++k) {
                const int i = tid + k * 256;
                const int c = i >> 6, n2 = i & 63;
                pre[k] = x[((size_t)b * C_ + (ch + 1) * 32 + c) * N_ + n0 + n2];
            }
        }
        const bf16x8 a = *reinterpret_cast<const bf16x8*>(&xs[buf][wave * 16 + l15][quad * 8]);
#pragma unroll
        for (int ot = 0; ot < 5; ++ot) {
            const int gro = oq * 5 + ot;
            const bf16x8 wb = *reinterpret_cast<const bf16x8*>(
                wcomb + (size_t)(gro * 16 + l15) * C_ + ch * 32 + quad * 8);
            acc[ot] = __builtin_amdgcn_mfma_f32_16x16x32_bf16(a, wb, acc[ot], 0, 0, 0);
        }
        if (ch < 7) {
#pragma unroll
            for (int k = 0; k < 8; ++k) {
                const int i = tid + k * 256;
                const int c = i >> 6, n2 = i & 63;
                xs[buf ^ 1][n2][c] = bf16_rne(pre[k]);
            }
        }
        __syncthreads();
    }
    const int n = n0 + wave * 16 + quad * 4;
#pragma unroll
    for (int ot = 0; ot < 5; ++ot) {
        const int gro = oq * 5 + ot;
        if (gro < 4) {
            const int o = gro * 16 + l15;
#pragma unroll
            for (int r = 0; r < 4; ++r)
                qkT[((size_t)b * N_ + n + r) * C4_ + o] = bf16_rne(acc[ot][r]);
        } else {
            const int c = (gro - 4) * 16 + l15;
            const float bb = bv[c];
            ushort4 u;
            u.x = bf16_rne(acc[ot][0] + bb);
            u.y = bf16_rne(acc[ot][1] + bb);
            u.z = bf16_rne(acc[ot][2] + bb);
            u.w = bf16_rne(acc[ot][3] + bb);
            *reinterpret_cast<ushort4*>(&v[((size_t)b * C_ + c) * N_ + n]) = u;
        }
    }
}

// rowsumraw[b,n] += sum_{m in quarter} exp(e[n,m]).  grid (64, 4 mq, B), 256 thr.
__global__ __launch_bounds__(256) void rowsum_kernel(
        const unsigned short* __restrict__ qkT, float* __restrict__ rowsumraw) {
    const int n0 = blockIdx.x * 64 + (threadIdx.x >> 6) * 16;
    const int mq = blockIdx.y;
    const int b = blockIdx.z;
    const int lane = threadIdx.x & 63;
    const int quad = lane >> 4, l15 = lane & 15;
    const unsigned short* qb = qkT + (size_t)b * N_ * C4_;
    const unsigned short* qrow = qb + (size_t)(n0 + l15) * C4_;
    const bf16x8 a0 = *reinterpret_cast<const bf16x8*>(qrow + quad * 8);
    const bf16x8 a1 = *reinterpret_cast<const bf16x8*>(qrow + 32 + quad * 8);
    float cs[4] = {};
#pragma unroll 2
    for (int m16 = mq * 1024; m16 < (mq + 1) * 1024; m16 += 16) {
        const unsigned short* krow = qb + (size_t)(m16 + l15) * C4_;
        const bf16x8 kb0 = *reinterpret_cast<const bf16x8*>(krow + quad * 8);
        const bf16x8 kb1 = *reinterpret_cast<const bf16x8*>(krow + 32 + quad * 8);
        f32x4 z = {0.f, 0.f, 0.f, 0.f};
        z = __builtin_amdgcn_mfma_f32_16x16x32_bf16(a0, kb0, z, 0, 0, 0);
        const f32x4 e = __builtin_amdgcn_mfma_f32_16x16x32_bf16(a1, kb1, z, 0, 0, 0);
#pragma unroll
        for (int r = 0; r < 4; ++r) cs[r] += __expf(e[r]);
    }
#pragma unroll
    for (int r = 0; r < 4; ++r) {
#pragma unroll
        for (int k = 1; k <= 8; k <<= 1) cs[r] += __shfl_xor(cs[r], k, 64);
        if (l15 == 0) atomicAdd(&rowsumraw[(size_t)b * N_ + n0 + quad * 4 + r], cs[r]);
    }
}

// passA: P~[b,n,m] = exp(e)*rowsuminv[n] (bf16, stored), colsumraw += col partials.
// grid (64 mtiles, 64 ntiles, B), 256 thr = 4 waves (n-strips).
__global__ __launch_bounds__(256) void passA_kernel(
        const unsigned short* __restrict__ qkT, const float* __restrict__ rowsumraw,
        float* __restrict__ colsumraw, unsigned short* __restrict__ pt) {
    __shared__ unsigned short pl[4][16][68];
    __shared__ float colred[4][64];
    const int m0 = blockIdx.x * 64;
    const int ntile = blockIdx.y;
    const int b = blockIdx.z;
    const int tid = threadIdx.x;
    const int wave = tid >> 6, lane = tid & 63;
    const int quad = lane >> 4, l15 = lane & 15;
    const int n0 = ntile * 64 + wave * 16;
    const unsigned short* qb = qkT + (size_t)b * N_ * C4_;
    const unsigned short* qrow = qb + (size_t)(n0 + l15) * C4_;
    const bf16x8 a0 = *reinterpret_cast<const bf16x8*>(qrow + quad * 8);
    const bf16x8 a1 = *reinterpret_cast<const bf16x8*>(qrow + 32 + quad * 8);
    float rsi[4];
#pragma unroll
    for (int r = 0; r < 4; ++r)
        rsi[r] = 1.0f / rowsumraw[(size_t)b * N_ + n0 + quad * 4 + r];
    float cp[4];
#pragma unroll
    for (int s = 0; s < 4; ++s) {
        const unsigned short* krow = qb + (size_t)(m0 + s * 16 + l15) * C4_;
        const bf16x8 kb0 = *reinterpret_cast<const bf16x8*>(krow + quad * 8);
        const bf16x8 kb1 = *reinterpret_cast<const bf16x8*>(krow + 32 + quad * 8);
        f32x4 z = {0.f, 0.f, 0.f, 0.f};
        z = __builtin_amdgcn_mfma_f32_16x16x32_bf16(a0, kb0, z, 0, 0, 0);
        const f32x4 e = __builtin_amdgcn_mfma_f32_16x16x32_bf16(a1, kb1, z, 0, 0, 0);
        float pv[4];
#pragma unroll
        for (int r = 0; r < 4; ++r) pv[r] = __expf(e[r]) * rsi[r];
        cp[s] = pv[0] + pv[1] + pv[2] + pv[3];
#pragma unroll
        for (int r = 0; r < 4; ++r)
            pl[wave][quad * 4 + r][s * 16 + l15] = bf16_rne(pv[r]);
    }
#pragma unroll
    for (int s = 0; s < 4; ++s) {
        cp[s] += __shfl_xor(cp[s], 16, 64);
        cp[s] += __shfl_xor(cp[s], 32, 64);
        if (quad == 0) colred[wave][s * 16 + l15] = cp[s];
    }
    // store P~ rows (same-wave LDS round trip, in-order DS)
    const size_t rowbase = ((size_t)b * N_ + n0 + l15) * N_ + m0;
    const bf16x8 r0 = *reinterpret_cast<const bf16x8*>(&pl[wave][l15][quad * 8]);
    const bf16x8 r1 = *reinterpret_cast<const bf16x8*>(&pl[wave][l15][32 + quad * 8]);
    *reinterpret_cast<bf16x8*>(&pt[rowbase + quad * 8]) = r0;
    *reinterpret_cast<bf16x8*>(&pt[rowbase + 32 + quad * 8]) = r1;
    __syncthreads();
    if (tid < 64) {
        const float t = colred[0][tid] + colred[1][tid] + colred[2][tid] + colred[3][tid];
        atomicAdd(&colsumraw[(size_t)b * N_ + m0 + tid], t);
    }
}

// vscale: vs[b,c,m] = v[b,c,m] / (1e-9 + colsumraw[b,m])  (bf16)
__global__ __launch_bounds__(256) void vscale_kernel(
        const unsigned short* __restrict__ vw, const float* __restrict__ colsumraw,
        unsigned short* __restrict__ vs) {
    const size_t idx = ((size_t)blockIdx.x * 256 + threadIdx.x) * 8;
    const int b = (int)(idx / ((size_t)C_ * N_));
    const int m0 = (int)(idx & (N_ - 1));
    const bf16x8 vv = *reinterpret_cast<const bf16x8*>(vw + idx);
    unsigned short o[8];
#pragma unroll
    for (int j = 0; j < 8; ++j) {
        const float ci = 1.0f / (1e-9f + colsumraw[(size_t)b * N_ + m0 + j]);
        o[j] = bf16_rne(bf16_to_f((unsigned short)vv[j]) * ci);
    }
    *reinterpret_cast<bf16x8*>(vs + idx) = *reinterpret_cast<bf16x8*>(o);
}

// passB: x_r = Vs * P~^T as a clean dbuf GEMM; fused wt GEMM + BN + ReLU + res.
// grid 512 (swizzled: b owns 2 XCDs), 512 thr = 8 waves = 4 cq x 2 ns.
__global__ __launch_bounds__(512) void passB_kernel(
        const float* __restrict__ x, const unsigned short* __restrict__ pt,
        const unsigned short* __restrict__ vs, const unsigned short* __restrict__ wtb,
        const float* __restrict__ bt, const float* __restrict__ gamma,
        const float* __restrict__ beta, const float* __restrict__ rmean,
        const float* __restrict__ rvar, float* __restrict__ out) {
    __shared__ union {
        struct {
            unsigned short vt[2][256][36];   // 36 KB
            unsigned short ptl[2][32][36];   // 4.5 KB
        } s;
        unsigned short dsm[32][268];         // 16.75 KB
    } u;
    const int L = blockIdx.x;
    const int b = (L & 7) >> 1;
    const int ntile = (L >> 3) * 2 + (L & 1);   // 0..127
    const int nb0 = ntile * 32;
    const int tid = threadIdx.x;
    const int wave = tid >> 6, lane = tid & 63;
    const int cq = wave & 3, ns = wave >> 2;
    const int quad = lane >> 4, l15 = lane & 15;
    const unsigned short* vb = vs + (size_t)b * C_ * N_;
    const unsigned short* pb = pt + ((size_t)b * N_ + nb0) * N_;
    // staging slots: vt: 1024 slots (row=slot>>2, ch=slot&3), 2 per thread
    const int s0r = tid >> 1;            // unused pattern replaced below
    (void)s0r;
    f32x4 acc[4];
#pragma unroll
    for (int j = 0; j < 4; ++j) acc[j] = (f32x4){0.f, 0.f, 0.f, 0.f};
    // prologue: stage k0 = 0 into buf 0
    {
        const int sl0 = tid, sl1 = tid + 512;
        const bf16x8 a = *reinterpret_cast<const bf16x8*>(vb + (size_t)(sl0 >> 2) * N_ + (sl0 & 3) * 8);
        const bf16x8 c = *reinterpret_cast<const bf16x8*>(vb + (size_t)(sl1 >> 2) * N_ + (sl1 & 3) * 8);
        *reinterpret_cast<bf16x8*>(&u.s.vt[0][sl0 >> 2][(sl0 & 3) * 8]) = a;
        *reinterpret_cast<bf16x8*>(&u.s.vt[0][sl1 >> 2][(sl1 & 3) * 8]) = c;
        if (tid < 128) {
            const bf16x8 p = *reinterpret_cast<const bf16x8*>(pb + (size_t)(tid >> 2) * N_ + (tid & 3) * 8);
            *reinterpret_cast<bf16x8*>(&u.s.ptl[0][tid >> 2][(tid & 3) * 8]) = p;
        }
    }
    __syncthreads();
    for (int kt = 0; kt < 128; ++kt) {
        const int buf = kt & 1;
        const int k0 = (kt + 1) * 32;
        bf16x8 pv0, pv1, pp;
        if (kt < 127) {
            const int sl0 = tid, sl1 = tid + 512;
            pv0 = *reinterpret_cast<const bf16x8*>(vb + (size_t)(sl0 >> 2) * N_ + k0 + (sl0 & 3) * 8);
            pv1 = *reinterpret_cast<const bf16x8*>(vb + (size_t)(sl1 >> 2) * N_ + k0 + (sl1 & 3) * 8);
            if (tid < 128)
                pp = *reinterpret_cast<const bf16x8*>(pb + (size_t)(tid >> 2) * N_ + k0 + (tid & 3) * 8);
        }
        const bf16x8 af = *reinterpret_cast<const bf16x8*>(&u.s.ptl[buf][ns * 16 + l15][quad * 8]);
#pragma unroll
        for (int j = 0; j < 4; ++j) {
            const bf16x8 bf = *reinterpret_cast<const bf16x8*>(
                &u.s.vt[buf][cq * 64 + j * 16 + l15][quad * 8]);
            acc[j] = __builtin_amdgcn_mfma_f32_16x16x32_bf16(af, bf, acc[j], 0, 0, 0);
        }
        if (kt < 127) {
            const int sl0 = tid, sl1 = tid + 512;
            *reinterpret_cast<bf16x8*>(&u.s.vt[buf ^ 1][sl0 >> 2][(sl0 & 3) * 8]) = pv0;
            *reinterpret_cast<bf16x8*>(&u.s.vt[buf ^ 1][sl1 >> 2][(sl1 & 3) * 8]) = pv1;
            if (tid < 128)
                *reinterpret_cast<bf16x8*>(&u.s.ptl[buf ^ 1][tid >> 2][(tid & 3) * 8]) = pp;
        }
        __syncthreads();
    }
    // dsm = x - x_r (bf16, A-layout [n][c])
#pragma unroll
    for (int j = 0; j < 4; ++j) {
        const int c = cq * 64 + j * 16 + l15;
        const float4 xv = *reinterpret_cast<const float4*>(
            &x[((size_t)b * C_ + c) * N_ + nb0 + ns * 16 + quad * 4]);
        const float xvr[4] = {xv.x, xv.y, xv.z, xv.w};
#pragma unroll
        for (int r = 0; r < 4; ++r)
            u.dsm[ns * 16 + quad * 4 + r][c] = bf16_rne(xvr[r] - acc[j][r]);
    }
    __syncthreads();
    bf16x8 da[8];
#pragma unroll
    for (int k = 0; k < 8; ++k)
        da[k] = *reinterpret_cast<const bf16x8*>(&u.dsm[ns * 16 + l15][k * 32 + quad * 8]);
    f32x4 tacc[4];
#pragma unroll
    for (int j = 0; j < 4; ++j) tacc[j] = (f32x4){0.f, 0.f, 0.f, 0.f};
#pragma unroll
    for (int j = 0; j < 4; ++j) {
        const int ot = cq * 4 + j;
#pragma unroll
        for (int k = 0; k < 8; ++k) {
            const bf16x8 wb = *reinterpret_cast<const bf16x8*>(
                wtb + (size_t)(ot * 16 + l15) * C_ + k * 32 + quad * 8);
            tacc[j] = __builtin_amdgcn_mfma_f32_16x16x32_bf16(da[k], wb, tacc[j], 0, 0, 0);
        }
    }
#pragma unroll
    for (int j = 0; j < 4; ++j) {
        const int o = (cq * 4 + j) * 16 + l15;
        const float g = gamma[o] * rsqrtf(rvar[o] + 1e-5f);
        const float mn = rmean[o], bbet = beta[o], bo = bt[o];
        const size_t oi = ((size_t)b * C_ + o) * N_ + nb0 + ns * 16 + quad * 4;
        const float4 xo = *reinterpret_cast<const float4*>(&x[oi]);
        float4 res;
        res.x = xo.x + fmaxf((tacc[j][0] + bo - mn) * g + bbet, 0.f);
        res.y = xo.y + fmaxf((tacc[j][1] + bo - mn) * g + bbet, 0.f);
        res.z = xo.z + fmaxf((tacc[j][2] + bo - mn) * g + bbet, 0.f);
        res.w = xo.w + fmaxf((tacc[j][3] + bo - mn) * g + bbet, 0.f);
        *reinterpret_cast<float4*>(&out[oi]) = res;
    }
}

}  // namespace

extern "C" void kernel_launch(void* const* d_in, const int* in_sizes, int n_in,
                              void* d_out, int out_size, void* d_ws, size_t ws_size,
                              hipStream_t stream) {
    const float* x = (const float*)d_in[0];
    const float* wq = (const float*)d_in[1];
    const float* wv = (const float*)d_in[2];
    const float* bv = (const float*)d_in[3];
    const float* wt = (const float*)d_in[4];
    const float* bt = (const float*)d_in[5];
    const float* gamma = (const float*)d_in[6];
    const float* beta = (const float*)d_in[7];
    const float* rmean = (const float*)d_in[8];
    const float* rvar = (const float*)d_in[9];
    float* out = (float*)d_out;

    char* base = (char*)d_ws;
    unsigned short* qkT = (unsigned short*)base;                               // 2 MB
    unsigned short* vw = (unsigned short*)(base + (size_t)(2u << 20));         // 8 MB
    unsigned short* vsc = (unsigned short*)(base + (size_t)(10u << 20));       // 8 MB
    unsigned short* wtb = (unsigned short*)(base + (size_t)(18u << 20));       // 128 KB
    unsigned short* wcomb = (unsigned short*)(base + (size_t)(18u << 20) + (128u << 10));
    float* rowsumraw = (float*)(base + (size_t)(18u << 20) + (288u << 10));    // 64 KB
    float* colsumraw = (float*)(base + (size_t)(18u << 20) + (352u << 10));    // 64 KB (contig)
    unsigned short* pt = (unsigned short*)(base + (size_t)(19u << 20));        // 128 MB

    cvt_kernel<<<dim3(144), dim3(256), 0, stream>>>(wq, wv, wt, wcomb, wtb);
    zero_kernel<<<dim3(128), dim3(256), 0, stream>>>(rowsumraw);  // rowsum+colsum 32768 floats
    proj_kernel<<<dim3(64, 4, B_), dim3(256), 0, stream>>>(x, wcomb, bv, qkT, vw);
    rowsum_kernel<<<dim3(64, 4, B_), dim3(256), 0, stream>>>(qkT, rowsumraw);
    passA_kernel<<<dim3(64, 64, B_), dim3(256), 0, stream>>>(qkT, rowsumraw, colsumraw, pt);
    vscale_kernel<<<dim3(2048), dim3(256), 0, stream>>>(vw, colsumraw, vsc);
    passB_kernel<<<dim3(512), dim3(512), 0, stream>>>(
        x, pt, vsc, wtb, bt, gamma, beta, rmean, rvar, out);
}